// Round 1
// baseline (582.412 us; speedup 1.0000x reference)
//
#include <hip/hip_runtime.h>

typedef unsigned long long u64;
typedef unsigned int u32;
typedef float v2f __attribute__((ext_vector_type(2)));

// Problem constants (from reference setup_inputs / NUM_GROUP / GROUP_SIZE)
#define BATCH 32
#define NPTS  8192
#define NGRP  512
#define KNN_K 32

#define FPS_T 256                  // fps block (4 waves) -- R4/R11 champion config
#define FPS_W (FPS_T / 64)         // 4 waves
#define PPAIR (NPTS / FPS_T / 2)   // 16 point-PAIRS per thread

#define KNN_WPB 8                  // knn waves per block (8 waves share LDS-staged tiles)
#define KNN_T   (KNN_WPB * 64)     // 512 threads
#define QCAP    128                // per-wave LDS candidate buffer depth
#define TP      1024               // staged tile size (points)
#define NT      (NPTS / TP)        // 8 tiles
#define NCOL    (TP / 64)          // 16 columns per tile
#define NCHUNK  (3 * TP / 256)     // 12 x 1KB global_load_lds chunks per tile

// Exact IEEE (no FMA contraction) squared distance: ((dx*dx + dy*dy) + dz*dz)
__device__ __forceinline__ float sq3(float dx, float dy, float dz) {
    return __fadd_rn(__fadd_rn(__fmul_rn(dx, dx), __fmul_rn(dy, dy)), __fmul_rn(dz, dz));
}

// d >= 0 always -> IEEE bits order-monotonic; u64 ascending == (d, idx) lex.
__device__ __forceinline__ u64 packdi(float d, int n) {
    return ((u64)__float_as_uint(d) << 32) | (u32)n;
}

__device__ __forceinline__ u64 umin64(u64 a, u64 b) { return a < b ? a : b; }
__device__ __forceinline__ u64 umax64(u64 a, u64 b) { return a > b ? a : b; }

__device__ __forceinline__ u64 shfl_xor_u64(u64 v, int m) {
    int lo = __shfl_xor((int)(u32)v, m, 64);
    int hi = __shfl_xor((int)(u32)(v >> 32), m, 64);
    return ((u64)(u32)hi << 32) | (u32)lo;
}

__device__ __forceinline__ u64 shfl_u64(u64 v, int src) {
    int lo = __shfl((int)(u32)v, src, 64);
    int hi = __shfl((int)(u32)(v >> 32), src, 64);
    return ((u64)(u32)hi << 32) | (u32)lo;
}

// ---- DPP wave-64 u64-max reduction (result valid in lane 63) --------------
// update_dpp(old=0, bound_ctrl=1): invalid-source lanes read 0; 0 is a safe
// identity (real keys have low32 = ~n >= 0xFFFFE000 > 0).
template <int CTRL>
__device__ __forceinline__ u64 dpp_max_step(u64 k) {
    u32 plo = (u32)__builtin_amdgcn_update_dpp(0, (int)(u32)k, CTRL, 0xF, 0xF, true);
    u32 phi = (u32)__builtin_amdgcn_update_dpp(0, (int)(u32)(k >> 32), CTRL, 0xF, 0xF, true);
    u64 p = ((u64)phi << 32) | plo;
    return k > p ? k : p;
}
__device__ __forceinline__ u64 dpp_wave_max(u64 k) {
    k = dpp_max_step<0x111>(k);  // row_shr:1
    k = dpp_max_step<0x112>(k);  // row_shr:2
    k = dpp_max_step<0x114>(k);  // row_shr:4
    k = dpp_max_step<0x118>(k);  // row_shr:8
    k = dpp_max_step<0x142>(k);  // row_bcast15
    k = dpp_max_step<0x143>(k);  // row_bcast31 -> lane63 = full wave
    return k;
}

// Cross-lane bitonic sort: one u64 per lane -> ascending by lane index.
__device__ __forceinline__ u64 lane_sort64(u64 v, int lane) {
#pragma unroll
    for (int k = 2; k <= 64; k <<= 1) {
#pragma unroll
        for (int j = k >> 1; j > 0; j >>= 1) {
            u64 p = shfl_xor_u64(v, j);
            bool keepmin = (((lane & k) == 0) == ((lane & j) == 0));
            u64 mn = umin64(v, p), mx = umax64(v, p);
            v = keepmin ? mn : mx;
        }
    }
    return v;
}

// m, c ascending-sorted across lanes -> lowest 64 of the 128, sorted.
__device__ __forceinline__ u64 lane_merge64(u64 m, u64 c, int lane) {
    u64 cr = shfl_xor_u64(c, 63);
    u64 z = umin64(m, cr);
#pragma unroll
    for (int dd = 32; dd > 0; dd >>= 1) {
        u64 p = shfl_xor_u64(z, dd);
        u64 mn = umin64(z, p), mx = umax64(z, p);
        z = (lane & dd) ? mx : mn;
    }
    return z;
}

// One knn scan step: tau-filter + ballot-compacted LDS append + batched flush
__device__ __forceinline__ void knn_step(u64& m, u64& tau, int& cnt, u64* sbuf,
                                         float x, float y, float z,
                                         float cx, float cy, float cz,
                                         int n, int lane) {
    float d = sq3(__fsub_rn(x, cx), __fsub_rn(y, cy), __fsub_rn(z, cz));
    u64 kk = packdi(d, n);
    bool cand = kk < tau;  // strict: excluded keys provably > global 32nd
    u64 mask = __ballot(cand);
    if (mask) {
        u32 below = __builtin_amdgcn_mbcnt_hi(
            (u32)(mask >> 32), __builtin_amdgcn_mbcnt_lo((u32)mask, 0));
        if (cand) sbuf[cnt + below] = kk;
        cnt += (int)__popcll(mask);
        if (cnt >= 64) {
            u64 c = sbuf[lane];
            c = lane_sort64(c, lane);
            m = lane_merge64(m, c, lane);
            tau = shfl_u64(m, 31);
            int rem = cnt - 64;
            if (lane < rem) sbuf[lane] = sbuf[64 + lane];
            cnt = rem;
        }
    }
}

// ---------------------------------------------------------------------------
// FPS (R4/R11 champion, 418 us measured 3x): one block per batch, 256
// threads, 32 points/thread as 16 float2 pairs (contract(off): per-op IEEE
// rounding == numpy). In-loop strict-> (bd,bi) tracking per half; u64
// (d_bits,~n) pack, 6-step DPP wave argmax, single barrier, double-buffered
// 4-partial exchange, scalar b32 coord broadcasts, LDS-buffered centers.
// 7 alternative structures (R5-R10, R12-R14) all regressed -- do not touch.
// UNCHANGED this round (isolated knn experiment).
// ---------------------------------------------------------------------------
__global__ __launch_bounds__(FPS_T) void fps_kernel(const float* __restrict__ in,
                                                    float* __restrict__ centers) {
#pragma clang fp contract(off)
    __shared__ float sx[NPTS];           // 32 KB
    __shared__ float sy[NPTS];           // 32 KB
    __shared__ float sz[NPTS];           // 32 KB
    __shared__ u64 s_key[2][FPS_W];      // double-buffered wave partials
    __shared__ float s_out[NGRP * 3];    // 6 KB center-coord buffer

    const int b = blockIdx.x;
    const int t = threadIdx.x;
    const int w = t >> 6;
    const float* xp = in + (size_t)b * 3 * NPTS;
    const float* yp = xp + NPTS;
    const float* zp = xp + 2 * NPTS;

    v2f xr[PPAIR], yr[PPAIR], zr[PPAIR], md[PPAIR];
#pragma unroll
    for (int i = 0; i < PPAIR; ++i) {
        int n = i * (2 * FPS_T) + 2 * t;       // pair covers points n, n+1
        xr[i] = *(const v2f*)(xp + n);
        yr[i] = *(const v2f*)(yp + n);
        zr[i] = *(const v2f*)(zp + n);
        *(v2f*)(sx + n) = xr[i];
        *(v2f*)(sy + n) = yr[i];
        *(v2f*)(sz + n) = zr[i];
        md[i] = (v2f){1e10f, 1e10f};
    }
    __syncthreads();

    int cur = 0;
    for (int r = 0; r < NGRP; ++r) {
        const float cx = sx[cur], cy = sy[cur], cz = sz[cur];  // b32 broadcasts
        if (t == 0) {  // idxs[r] is the PRE-update farthest -> buffer coords
            s_out[r * 3 + 0] = cx;
            s_out[r * 3 + 1] = cy;
            s_out[r * 3 + 2] = cz;
        }

        float bd0 = -1.0f, bd1 = -1.0f;
        int   bi0 = 0,     bi1 = 0;
#pragma unroll
        for (int i = 0; i < PPAIR; ++i) {
            v2f dx = xr[i] - cx;
            v2f dy = yr[i] - cy;
            v2f dz = zr[i] - cz;
            v2f dd = dx * dx + dy * dy + dz * dz;  // contract(off): 3 mul + 2 add
            md[i] = __builtin_elementwise_min(md[i], dd);
            int n = i * (2 * FPS_T) + 2 * t;
            if (md[i].x > bd0) { bd0 = md[i].x; bi0 = n; }      // strict >: first max
            if (md[i].y > bd1) { bd1 = md[i].y; bi1 = n + 1; }
        }
        // max (d, tie -> lowest n) == u64 max of (d_bits, ~n)
        u64 k0 = ((u64)__float_as_uint(bd0) << 32) | (u32)(~(u32)bi0);
        u64 k1 = ((u64)__float_as_uint(bd1) << 32) | (u32)(~(u32)bi1);
        u64 k = dpp_wave_max(umax64(k0, k1));
        if ((t & 63) == 63) s_key[r & 1][w] = k;  // lane 63 holds wave winner
        __syncthreads();
        u64 m = umax64(umax64(s_key[r & 1][0], s_key[r & 1][1]),
                       umax64(s_key[r & 1][2], s_key[r & 1][3]));
        cur = (int)(~(u32)m);  // recover winning index
    }

    __syncthreads();  // t0's last s_out writes
    float* cdst = centers + (size_t)b * NGRP * 3;
    for (int i = t; i < NGRP * 3; i += FPS_T) cdst[i] = s_out[i];
}

// ---------------------------------------------------------------------------
// kNN v2: block-cooperative double-buffered LDS staging. Previously each of
// 16384 waves streamed all 8192 points as 3 scalar global loads/point
// (1.5 GB L2 traffic, ~5x latency-bound at ~150 us). Now 8 waves/block share
// tiles staged via global_load_lds width=16 (issue-early at tile start,
// __syncthreads provides the vmcnt(0) drain + barrier at tile end). Scan
// becomes stride-1 conflict-free ds_read_b32; 32 KB LDS + 512 thr -> 4
// blocks/CU (8 waves/SIMD) so LDS latency hides under TLP. Global/L2
// traffic drops 8x. Exact top-32 core (tau filter, bitonic sort/merge)
// unchanged -> bit-exact output preserved.
// ---------------------------------------------------------------------------
__device__ __forceinline__ void stage_tile(const float* __restrict__ xp,
                                           float (*dst)[TP], int t,
                                           int wave, int lane) {
    // 12 chunks of 1 KB (64 lanes x 16B): chunk c -> plane c/4, 256-float slot c%4
    for (int c = wave; c < NCHUNK; c += KNN_WPB) {
        const int plane = c >> 2;
        const int off = (c & 3) << 8;  // *256 floats
        const float* gs = xp + (size_t)plane * NPTS + t * TP + off + lane * 4;
        __builtin_amdgcn_global_load_lds(
            (const __attribute__((address_space(1))) void*)gs,
            (__attribute__((address_space(3))) void*)&dst[plane][off],
            16, 0, 0);
    }
}

__global__ __launch_bounds__(KNN_T) void knn_kernel(const float* __restrict__ in,
                                                    const float* __restrict__ centers,
                                                    float* __restrict__ out) {
    __shared__ float stg[2][3][TP];      // 24 KB double-buffered point tiles
    __shared__ u64 sbuf[KNN_WPB][QCAP];  // 8 KB candidate buffers

    const int wave = threadIdx.x >> 6;
    const int lane = threadIdx.x & 63;
    const int cid  = blockIdx.x * KNN_WPB + wave;   // [0, B*G); 8 waves same batch
    const int b    = cid >> 9;                      // /NGRP

    const float* xp = in + (size_t)b * 3 * NPTS;
    const float* yp = xp + NPTS;
    const float* zp = xp + 2 * NPTS;

    const float cx = centers[cid * 3 + 0];
    const float cy = centers[cid * 3 + 1];
    const float cz = centers[cid * 3 + 2];

    stage_tile(xp, stg[0], 0, wave, lane);
    __syncthreads();  // drains this wave's vmcnt + barrier: tile 0 resident

    // seed: points 0..63 from LDS, exact sorted top-64
    float xs = stg[0][0][lane], ys = stg[0][1][lane], zs = stg[0][2][lane];
    u64 m = packdi(sq3(__fsub_rn(xs, cx), __fsub_rn(ys, cy), __fsub_rn(zs, cz)), lane);
    m = lane_sort64(m, lane);
    u64 tau = shfl_u64(m, 31);
    int cnt = 0;  // wave-uniform buffered-candidate count

#pragma unroll 1
    for (int t = 0; t < NT; ++t) {
        if (t + 1 < NT) stage_tile(xp, stg[(t + 1) & 1], t + 1, wave, lane);  // issue early
        const float* bx = stg[t & 1][0];
        const float* by = stg[t & 1][1];
        const float* bz = stg[t & 1][2];
        const int base = t * TP;
        int j = (t == 0) ? 1 : 0;  // tile 0 column 0 consumed by the seed
#pragma unroll 1
        for (; j + 3 < NCOL; j += 4) {
            int p0 = j * 64 + lane, p1 = p0 + 64, p2 = p0 + 128, p3 = p0 + 192;
            float x0 = bx[p0], y0 = by[p0], z0 = bz[p0];
            float x1 = bx[p1], y1 = by[p1], z1 = bz[p1];
            float x2 = bx[p2], y2 = by[p2], z2 = bz[p2];
            float x3 = bx[p3], y3 = by[p3], z3 = bz[p3];
            knn_step(m, tau, cnt, sbuf[wave], x0, y0, z0, cx, cy, cz, base + p0, lane);
            knn_step(m, tau, cnt, sbuf[wave], x1, y1, z1, cx, cy, cz, base + p1, lane);
            knn_step(m, tau, cnt, sbuf[wave], x2, y2, z2, cx, cy, cz, base + p2, lane);
            knn_step(m, tau, cnt, sbuf[wave], x3, y3, z3, cx, cy, cz, base + p3, lane);
        }
        for (; j < NCOL; ++j) {
            int p = j * 64 + lane;
            knn_step(m, tau, cnt, sbuf[wave], bx[p], by[p], bz[p], cx, cy, cz, base + p, lane);
        }
        __syncthreads();  // wave's next-tile loads landed; all waves done with tile t
    }

    // drain leftovers (<= 127 keys -> at most 2 batches)
    while (cnt > 0) {
        int take = cnt < 64 ? cnt : 64;
        u64 v = sbuf[wave][lane];
        u64 c = (lane < take) ? v : ~0ull;
        c = lane_sort64(c, lane);
        m = lane_merge64(m, c, lane);
        int rem = cnt - take;
        if (lane < rem) sbuf[wave][lane] = sbuf[wave][64 + lane];
        cnt = rem;
    }

    // lanes 0..31 hold the exact global top-32, ascending (== stable top_k)
    if (lane < KNN_K) {
        int n = (int)(u32)m;
        size_t o = (size_t)cid * (KNN_K * 3) + (size_t)lane * 3;
        out[o + 0] = __fsub_rn(xp[n], cx);
        out[o + 1] = __fsub_rn(yp[n], cy);
        out[o + 2] = __fsub_rn(zp[n], cz);
    }
}

extern "C" void kernel_launch(void* const* d_in, const int* in_sizes, int n_in,
                              void* d_out, int out_size, void* d_ws, size_t ws_size,
                              hipStream_t stream) {
    const float* in  = (const float*)d_in[0];
    float* out       = (float*)d_out;
    float* centers   = out + (size_t)BATCH * NGRP * KNN_K * 3;  // second output section

    fps_kernel<<<BATCH, FPS_T, 0, stream>>>(in, centers);
    knn_kernel<<<(BATCH * NGRP) / KNN_WPB, KNN_T, 0, stream>>>(in, centers, out);
}

// Round 3
// 557.699 us; speedup vs baseline: 1.0443x; 1.0443x over previous
//
#include <hip/hip_runtime.h>

typedef unsigned long long u64;
typedef unsigned int u32;
typedef float v2f __attribute__((ext_vector_type(2)));

// Problem constants (from reference setup_inputs / NUM_GROUP / GROUP_SIZE)
#define BATCH 32
#define NPTS  8192
#define NGRP  512
#define KNN_K 32

#define FPS_T 256                  // fps block (4 waves) -- R4/R11 champion config
#define FPS_W (FPS_T / 64)         // 4 waves
#define PPAIR (NPTS / FPS_T / 2)   // 16 point-PAIRS per thread

#define KNN_WPB 8                  // knn waves per block
#define KNN_T   (KNN_WPB * 64)     // 512 threads
#define QCAP    128                // per-wave LDS candidate buffer depth

#define NCH     (NPTS / 64)        // 128 sorted 64-point chunks per batch
#define GC      16                 // grid cells per axis (16^3 = 4096)
#define NCELL   (GC * GC * GC)
#define BT      512                // build_kernel threads
#define BPT     (NPTS / BT)        // 16 points per build thread
// Workspace layout per batch (floats): sx[8192] sy[8192] sz[8192] sidx[8192(u32)] aabb[128*6]
#define WSF     (4 * NPTS + NCH * 6)   // 33536 floats per batch

// Exact IEEE (no FMA contraction) squared distance: ((dx*dx + dy*dy) + dz*dz)
__device__ __forceinline__ float sq3(float dx, float dy, float dz) {
    return __fadd_rn(__fadd_rn(__fmul_rn(dx, dx), __fmul_rn(dy, dy)), __fmul_rn(dz, dz));
}

// d >= 0 always -> IEEE bits order-monotonic; u64 ascending == (d, idx) lex.
__device__ __forceinline__ u64 packdi(float d, int n) {
    return ((u64)__float_as_uint(d) << 32) | (u32)n;
}

__device__ __forceinline__ u64 umin64(u64 a, u64 b) { return a < b ? a : b; }
__device__ __forceinline__ u64 umax64(u64 a, u64 b) { return a > b ? a : b; }

__device__ __forceinline__ u64 shfl_xor_u64(u64 v, int m) {
    int lo = __shfl_xor((int)(u32)v, m, 64);
    int hi = __shfl_xor((int)(u32)(v >> 32), m, 64);
    return ((u64)(u32)hi << 32) | (u32)lo;
}

__device__ __forceinline__ u64 shfl_u64(u64 v, int src) {
    int lo = __shfl((int)(u32)v, src, 64);
    int hi = __shfl((int)(u32)(v >> 32), src, 64);
    return ((u64)(u32)hi << 32) | (u32)lo;
}

// ---- DPP wave-64 u64-max reduction (result valid in lane 63) --------------
// update_dpp(old=0, bound_ctrl=1): invalid-source lanes read 0; 0 is a safe
// identity (for the min-pick use below, key ~0 means "consumed" and ~key==0).
template <int CTRL>
__device__ __forceinline__ u64 dpp_max_step(u64 k) {
    u32 plo = (u32)__builtin_amdgcn_update_dpp(0, (int)(u32)k, CTRL, 0xF, 0xF, true);
    u32 phi = (u32)__builtin_amdgcn_update_dpp(0, (int)(u32)(k >> 32), CTRL, 0xF, 0xF, true);
    u64 p = ((u64)phi << 32) | plo;
    return k > p ? k : p;
}
__device__ __forceinline__ u64 dpp_wave_max(u64 k) {
    k = dpp_max_step<0x111>(k);  // row_shr:1
    k = dpp_max_step<0x112>(k);  // row_shr:2
    k = dpp_max_step<0x114>(k);  // row_shr:4
    k = dpp_max_step<0x118>(k);  // row_shr:8
    k = dpp_max_step<0x142>(k);  // row_bcast15
    k = dpp_max_step<0x143>(k);  // row_bcast31 -> lane63 = full wave
    return k;
}

// Cross-lane bitonic sort: one u64 per lane -> ascending by lane index.
__device__ __forceinline__ u64 lane_sort64(u64 v, int lane) {
#pragma unroll
    for (int k = 2; k <= 64; k <<= 1) {
#pragma unroll
        for (int j = k >> 1; j > 0; j >>= 1) {
            u64 p = shfl_xor_u64(v, j);
            bool keepmin = (((lane & k) == 0) == ((lane & j) == 0));
            u64 mn = umin64(v, p), mx = umax64(v, p);
            v = keepmin ? mn : mx;
        }
    }
    return v;
}

// m, c ascending-sorted across lanes -> lowest 64 of the 128, sorted.
__device__ __forceinline__ u64 lane_merge64(u64 m, u64 c, int lane) {
    u64 cr = shfl_xor_u64(c, 63);
    u64 z = umin64(m, cr);
#pragma unroll
    for (int dd = 32; dd > 0; dd >>= 1) {
        u64 p = shfl_xor_u64(z, dd);
        u64 mn = umin64(z, p), mx = umax64(z, p);
        z = (lane & dd) ? mx : mn;
    }
    return z;
}

// One knn scan step: tau-filter + ballot-compacted LDS append + batched flush
__device__ __forceinline__ void knn_step(u64& m, u64& tau, int& cnt, u64* sbuf,
                                         float x, float y, float z,
                                         float cx, float cy, float cz,
                                         int n, int lane) {
    float d = sq3(__fsub_rn(x, cx), __fsub_rn(y, cy), __fsub_rn(z, cz));
    u64 kk = packdi(d, n);
    bool cand = kk < tau;  // strict: excluded keys provably > global 32nd
    u64 mask = __ballot(cand);
    if (mask) {
        u32 below = __builtin_amdgcn_mbcnt_hi(
            (u32)(mask >> 32), __builtin_amdgcn_mbcnt_lo((u32)mask, 0));
        if (cand) sbuf[cnt + below] = kk;
        cnt += (int)__popcll(mask);
        if (cnt >= 64) {
            u64 c = sbuf[lane];
            c = lane_sort64(c, lane);
            m = lane_merge64(m, c, lane);
            tau = shfl_u64(m, 31);
            int rem = cnt - 64;
            if (lane < rem) sbuf[lane] = sbuf[64 + lane];
            cnt = rem;
        }
    }
}

// ---------------------------------------------------------------------------
// FPS (R4/R11 champion, 418 us measured 3x): one block per batch, 256
// threads, 32 points/thread as 16 float2 pairs (contract(off): per-op IEEE
// rounding == numpy). In-loop strict-> (bd,bi) tracking per half; u64
// (d_bits,~n) pack, 6-step DPP wave argmax, single barrier, double-buffered
// 4-partial exchange, scalar b32 coord broadcasts, LDS-buffered centers.
// 7 alternative structures (R5-R10, R12-R14) all regressed -- do not touch.
// UNCHANGED this round (isolated knn experiment; R2 bench was an infra
// failure with no pytest/profile stages -- resubmitting unchanged).
// ---------------------------------------------------------------------------
__global__ __launch_bounds__(FPS_T) void fps_kernel(const float* __restrict__ in,
                                                    float* __restrict__ centers) {
#pragma clang fp contract(off)
    __shared__ float sx[NPTS];           // 32 KB
    __shared__ float sy[NPTS];           // 32 KB
    __shared__ float sz[NPTS];           // 32 KB
    __shared__ u64 s_key[2][FPS_W];      // double-buffered wave partials
    __shared__ float s_out[NGRP * 3];    // 6 KB center-coord buffer

    const int b = blockIdx.x;
    const int t = threadIdx.x;
    const int w = t >> 6;
    const float* xp = in + (size_t)b * 3 * NPTS;
    const float* yp = xp + NPTS;
    const float* zp = xp + 2 * NPTS;

    v2f xr[PPAIR], yr[PPAIR], zr[PPAIR], md[PPAIR];
#pragma unroll
    for (int i = 0; i < PPAIR; ++i) {
        int n = i * (2 * FPS_T) + 2 * t;       // pair covers points n, n+1
        xr[i] = *(const v2f*)(xp + n);
        yr[i] = *(const v2f*)(yp + n);
        zr[i] = *(const v2f*)(zp + n);
        *(v2f*)(sx + n) = xr[i];
        *(v2f*)(sy + n) = yr[i];
        *(v2f*)(sz + n) = zr[i];
        md[i] = (v2f){1e10f, 1e10f};
    }
    __syncthreads();

    int cur = 0;
    for (int r = 0; r < NGRP; ++r) {
        const float cx = sx[cur], cy = sy[cur], cz = sz[cur];  // b32 broadcasts
        if (t == 0) {  // idxs[r] is the PRE-update farthest -> buffer coords
            s_out[r * 3 + 0] = cx;
            s_out[r * 3 + 1] = cy;
            s_out[r * 3 + 2] = cz;
        }

        float bd0 = -1.0f, bd1 = -1.0f;
        int   bi0 = 0,     bi1 = 0;
#pragma unroll
        for (int i = 0; i < PPAIR; ++i) {
            v2f dx = xr[i] - cx;
            v2f dy = yr[i] - cy;
            v2f dz = zr[i] - cz;
            v2f dd = dx * dx + dy * dy + dz * dz;  // contract(off): 3 mul + 2 add
            md[i] = __builtin_elementwise_min(md[i], dd);
            int n = i * (2 * FPS_T) + 2 * t;
            if (md[i].x > bd0) { bd0 = md[i].x; bi0 = n; }      // strict >: first max
            if (md[i].y > bd1) { bd1 = md[i].y; bi1 = n + 1; }
        }
        // max (d, tie -> lowest n) == u64 max of (d_bits, ~n)
        u64 k0 = ((u64)__float_as_uint(bd0) << 32) | (u32)(~(u32)bi0);
        u64 k1 = ((u64)__float_as_uint(bd1) << 32) | (u32)(~(u32)bi1);
        u64 k = dpp_wave_max(umax64(k0, k1));
        if ((t & 63) == 63) s_key[r & 1][w] = k;  // lane 63 holds wave winner
        __syncthreads();
        u64 m = umax64(umax64(s_key[r & 1][0], s_key[r & 1][1]),
                       umax64(s_key[r & 1][2], s_key[r & 1][3]));
        cur = (int)(~(u32)m);  // recover winning index
    }

    __syncthreads();  // t0's last s_out writes
    float* cdst = centers + (size_t)b * NGRP * 3;
    for (int i = t; i < NGRP * 3; i += FPS_T) cdst[i] = s_out[i];
}

// ---------------------------------------------------------------------------
// build_kernel: per-batch Morton counting-sort + per-chunk AABBs.
// One block per batch. Scatter order within a cell is nondeterministic (LDS
// atomics) but the knn selection is a scan-order-independent lex-min over
// u64 (d_bits, orig_idx) keys, so output bits are unaffected. AABBs are
// computed from the actual sorted points -> pruning soundness never depends
// on the grid itself (grid quality only affects speed).
// ---------------------------------------------------------------------------
__device__ __forceinline__ int cell_of(float v) {
    int c = (int)((v + 4.0f) * 2.0f);
    c = c < 0 ? 0 : c;
    return c > (GC - 1) ? (GC - 1) : c;
}
__device__ __forceinline__ u32 part3_4(u32 v) {  // spread 4 bits to bits 0,3,6,9
    return (v & 1u) | ((v & 2u) << 2) | ((v & 4u) << 4) | ((v & 8u) << 6);
}

__global__ __launch_bounds__(BT) void build_kernel(const float* __restrict__ in,
                                                   float* __restrict__ ws) {
    __shared__ u32 hist[NCELL];     // 16 KB
    __shared__ float sxl[NPTS];     // 32 KB
    __shared__ float syl[NPTS];     // 32 KB
    __shared__ float szl[NPTS];     // 32 KB  (total ~112 KB; 1 block/CU, fine)
    __shared__ u32 wtot[BT / 64];

    const int b = blockIdx.x;
    const int t = threadIdx.x;
    const int lane = t & 63;
    const int w = t >> 6;
    const float* xp = in + (size_t)b * 3 * NPTS;
    const float* yp = xp + NPTS;
    const float* zp = xp + 2 * NPTS;
    float* wsb = ws + (size_t)b * WSF;
    float* ws_sx = wsb;
    float* ws_sy = wsb + NPTS;
    float* ws_sz = wsb + 2 * NPTS;
    u32*   ws_si = (u32*)(wsb + 3 * NPTS);
    float* ws_ab = wsb + 4 * NPTS;

    for (int i = t; i < NCELL; i += BT) hist[i] = 0;
    __syncthreads();

    float px[BPT], py[BPT], pz[BPT];
    int pc[BPT];
#pragma unroll
    for (int i = 0; i < BPT; ++i) {
        int n = i * BT + t;  // coalesced
        float x = xp[n], y = yp[n], z = zp[n];
        px[i] = x; py[i] = y; pz[i] = z;
        pc[i] = (int)(part3_4((u32)cell_of(x)) | (part3_4((u32)cell_of(y)) << 1) |
                      (part3_4((u32)cell_of(z)) << 2));
        atomicAdd(&hist[pc[i]], 1u);
    }
    __syncthreads();

    // exclusive scan of hist[4096]: 8 cells/thread + wave scan + cross-wave
    u32 h[NCELL / BT];
    u32 lsum = 0;
#pragma unroll
    for (int j = 0; j < NCELL / BT; ++j) { h[j] = hist[t * (NCELL / BT) + j]; lsum += h[j]; }
    u32 x = lsum;
#pragma unroll
    for (int d = 1; d < 64; d <<= 1) {
        u32 y = __shfl_up(x, d, 64);
        if (lane >= d) x += y;
    }
    if (lane == 63) wtot[w] = x;
    u32 wexcl = x - lsum;
    __syncthreads();
    u32 base = 0;
    for (int j = 0; j < w; ++j) base += wtot[j];
    u32 run = base + wexcl;
#pragma unroll
    for (int j = 0; j < NCELL / BT; ++j) {
        u32 c = h[j];
        hist[t * (NCELL / BT) + j] = run;
        run += c;
    }
    __syncthreads();

    // scatter into LDS (coords) + global (orig index)
#pragma unroll
    for (int i = 0; i < BPT; ++i) {
        u32 pos = atomicAdd(&hist[pc[i]], 1u);
        sxl[pos] = px[i]; syl[pos] = py[i]; szl[pos] = pz[i];
        ws_si[pos] = (u32)(i * BT + t);
    }
    __syncthreads();

    // write sorted coords out, coalesced
    for (int i = t; i < NPTS; i += BT) {
        ws_sx[i] = sxl[i]; ws_sy[i] = syl[i]; ws_sz[i] = szl[i];
    }
    // per-chunk AABB: 128 chunks / 8 waves
    for (int q = w; q < NCH; q += BT / 64) {
        int p = q * 64 + lane;
        float X = sxl[p], Y = syl[p], Z = szl[p];
        float xlo = X, xhi = X, ylo = Y, yhi = Y, zlo = Z, zhi = Z;
#pragma unroll
        for (int d = 1; d < 64; d <<= 1) {
            xlo = fminf(xlo, __shfl_xor(xlo, d, 64)); xhi = fmaxf(xhi, __shfl_xor(xhi, d, 64));
            ylo = fminf(ylo, __shfl_xor(ylo, d, 64)); yhi = fmaxf(yhi, __shfl_xor(yhi, d, 64));
            zlo = fminf(zlo, __shfl_xor(zlo, d, 64)); zhi = fmaxf(zhi, __shfl_xor(zhi, d, 64));
        }
        if (lane == 0) {
            float* a = ws_ab + q * 6;
            a[0] = xlo; a[1] = xhi; a[2] = ylo; a[3] = yhi; a[4] = zlo; a[5] = zhi;
        }
    }
}

// ---------------------------------------------------------------------------
// kNN v3: chunk-pruned exact top-32. Per wave: 128 chunk AABB lower bounds
// (2/lane, in regs as (lb_bits<<32)|chunk u64 keys), DPP-min-pick nearest
// chunk, seed exact top-64 from it, then pick+tau-filter until
// lb*0.999 > tau_d (margin >> float rounding error -> skips provably can't
// touch the exact top-32; processed points use the identical sq3/key
// arithmetic as before). Expected ~6-12 of 128 chunks per wave.
// ---------------------------------------------------------------------------
__global__ __launch_bounds__(KNN_T) void knn_kernel(const float* __restrict__ in,
                                                    const float* __restrict__ centers,
                                                    const float* __restrict__ ws,
                                                    float* __restrict__ out) {
    __shared__ float s_ab[NCH * 6];      // 3 KB chunk AABBs (shared: whole block same batch)
    __shared__ u64 sbuf[KNN_WPB][QCAP];  // 8 KB candidate buffers

    const int wave = threadIdx.x >> 6;
    const int lane = threadIdx.x & 63;
    const int cid  = blockIdx.x * KNN_WPB + wave;   // [0, B*G); 8 waves same batch
    const int b    = cid >> 9;                      // /NGRP

    const float* xp = in + (size_t)b * 3 * NPTS;
    const float* yp = xp + NPTS;
    const float* zp = xp + 2 * NPTS;
    const float* wsb = ws + (size_t)b * WSF;
    const float* sxs = wsb;
    const float* sys = wsb + NPTS;
    const float* szs = wsb + 2 * NPTS;
    const u32*   sidx = (const u32*)(wsb + 3 * NPTS);
    const float* ab = wsb + 4 * NPTS;

    for (int i = threadIdx.x; i < NCH * 6; i += KNN_T) s_ab[i] = ab[i];
    __syncthreads();

    const float cx = centers[cid * 3 + 0];
    const float cy = centers[cid * 3 + 1];
    const float cz = centers[cid * 3 + 2];

    // per-lane lower-bound keys for chunks lane and lane+64
    u64 k0, k1;
    {
        const float* a0 = &s_ab[lane * 6];
        float dx = fmaxf(fmaxf(__fsub_rn(a0[0], cx), __fsub_rn(cx, a0[1])), 0.0f);
        float dy = fmaxf(fmaxf(__fsub_rn(a0[2], cy), __fsub_rn(cy, a0[3])), 0.0f);
        float dz = fmaxf(fmaxf(__fsub_rn(a0[4], cz), __fsub_rn(cz, a0[5])), 0.0f);
        k0 = ((u64)__float_as_uint(dx * dx + dy * dy + dz * dz) << 32) | (u32)lane;
        const float* a1 = &s_ab[(lane + 64) * 6];
        dx = fmaxf(fmaxf(__fsub_rn(a1[0], cx), __fsub_rn(cx, a1[1])), 0.0f);
        dy = fmaxf(fmaxf(__fsub_rn(a1[2], cy), __fsub_rn(cy, a1[3])), 0.0f);
        dz = fmaxf(fmaxf(__fsub_rn(a1[4], cz), __fsub_rn(cz, a1[5])), 0.0f);
        k1 = ((u64)__float_as_uint(dx * dx + dy * dy + dz * dz) << 32) | (u32)(lane + 64);
    }

    u64 m, tau;
    int cnt = 0;

    // seed: nearest chunk, exact sorted top-64
    {
        u64 inv = dpp_wave_max(~umin64(k0, k1));
        u64 got = ~shfl_u64(inv, 63);
        int c = (int)(u32)got;
        int p = c * 64 + lane;
        float X = sxs[p], Y = sys[p], Z = szs[p];
        int n = (int)sidx[p];
        m = lane_sort64(packdi(sq3(__fsub_rn(X, cx), __fsub_rn(Y, cy), __fsub_rn(Z, cz)), n),
                        lane);
        tau = shfl_u64(m, 31);
        if (lane == (c & 63)) { if (c < 64) k0 = ~0ull; else k1 = ~0ull; }
    }

    // pick+filter loop: chunks in ascending lb order, sound early break
    for (int it = 1; it < NCH; ++it) {
        u64 inv = dpp_wave_max(~umin64(k0, k1));
        u64 got = ~shfl_u64(inv, 63);
        float lb = __uint_as_float((u32)(got >> 32));
        float tau_d = __uint_as_float((u32)(tau >> 32));
        if (lb * 0.999f > tau_d) break;  // all remaining chunks provably > 32nd
        int c = (int)(u32)got;
        int p = c * 64 + lane;
        float X = sxs[p], Y = sys[p], Z = szs[p];
        int n = (int)sidx[p];
        knn_step(m, tau, cnt, sbuf[wave], X, Y, Z, cx, cy, cz, n, lane);
        if (lane == (c & 63)) { if (c < 64) k0 = ~0ull; else k1 = ~0ull; }
    }

    // drain leftovers (<= 127 keys -> at most 2 batches)
    while (cnt > 0) {
        int take = cnt < 64 ? cnt : 64;
        u64 v = sbuf[wave][lane];
        u64 c = (lane < take) ? v : ~0ull;
        c = lane_sort64(c, lane);
        m = lane_merge64(m, c, lane);
        int rem = cnt - take;
        if (lane < rem) sbuf[wave][lane] = sbuf[wave][64 + lane];
        cnt = rem;
    }

    // lanes 0..31 hold the exact global top-32, ascending (== stable top_k)
    if (lane < KNN_K) {
        int n = (int)(u32)m;
        size_t o = (size_t)cid * (KNN_K * 3) + (size_t)lane * 3;
        out[o + 0] = __fsub_rn(xp[n], cx);
        out[o + 1] = __fsub_rn(yp[n], cy);
        out[o + 2] = __fsub_rn(zp[n], cz);
    }
}

// ---------------------------------------------------------------------------
// Fallback knn (R0 champion, full scan) -- used only if ws_size is too small.
// ---------------------------------------------------------------------------
#define KNN_WPB_FB 4
__global__ __launch_bounds__(KNN_WPB_FB * 64) void knn_fallback(
    const float* __restrict__ in, const float* __restrict__ centers,
    float* __restrict__ out) {
    __shared__ u64 sbuf[KNN_WPB_FB][QCAP];

    const int wave = threadIdx.x >> 6;
    const int lane = threadIdx.x & 63;
    const int cid  = blockIdx.x * KNN_WPB_FB + wave;
    const int b    = cid >> 9;

    const float* xp = in + (size_t)b * 3 * NPTS;
    const float* yp = xp + NPTS;
    const float* zp = xp + 2 * NPTS;

    const float cx = centers[cid * 3 + 0];
    const float cy = centers[cid * 3 + 1];
    const float cz = centers[cid * 3 + 2];

    float x = xp[lane], y = yp[lane], z = zp[lane];
    u64 m = packdi(sq3(__fsub_rn(x, cx), __fsub_rn(y, cy), __fsub_rn(z, cz)), lane);
    m = lane_sort64(m, lane);
    u64 tau = shfl_u64(m, 31);
    int cnt = 0;

    int j = 1;
#pragma unroll 1
    for (; j + 3 < NPTS / 64; j += 4) {
        int n0 = j * 64 + lane, n1 = n0 + 64, n2 = n0 + 128, n3 = n0 + 192;
        float x0 = xp[n0], y0 = yp[n0], z0 = zp[n0];
        float x1 = xp[n1], y1 = yp[n1], z1 = zp[n1];
        float x2 = xp[n2], y2 = yp[n2], z2 = zp[n2];
        float x3 = xp[n3], y3 = yp[n3], z3 = zp[n3];
        knn_step(m, tau, cnt, sbuf[wave], x0, y0, z0, cx, cy, cz, n0, lane);
        knn_step(m, tau, cnt, sbuf[wave], x1, y1, z1, cx, cy, cz, n1, lane);
        knn_step(m, tau, cnt, sbuf[wave], x2, y2, z2, cx, cy, cz, n2, lane);
        knn_step(m, tau, cnt, sbuf[wave], x3, y3, z3, cx, cy, cz, n3, lane);
    }
    for (; j < NPTS / 64; ++j) {
        int n = j * 64 + lane;
        knn_step(m, tau, cnt, sbuf[wave], xp[n], yp[n], zp[n], cx, cy, cz, n, lane);
    }
    while (cnt > 0) {
        int take = cnt < 64 ? cnt : 64;
        u64 v = sbuf[wave][lane];
        u64 c = (lane < take) ? v : ~0ull;
        c = lane_sort64(c, lane);
        m = lane_merge64(m, c, lane);
        int rem = cnt - take;
        if (lane < rem) sbuf[wave][lane] = sbuf[wave][64 + lane];
        cnt = rem;
    }
    if (lane < KNN_K) {
        int n = (int)(u32)m;
        size_t o = (size_t)cid * (KNN_K * 3) + (size_t)lane * 3;
        out[o + 0] = __fsub_rn(xp[n], cx);
        out[o + 1] = __fsub_rn(yp[n], cy);
        out[o + 2] = __fsub_rn(zp[n], cz);
    }
}

extern "C" void kernel_launch(void* const* d_in, const int* in_sizes, int n_in,
                              void* d_out, int out_size, void* d_ws, size_t ws_size,
                              hipStream_t stream) {
    const float* in  = (const float*)d_in[0];
    float* out       = (float*)d_out;
    float* centers   = out + (size_t)BATCH * NGRP * KNN_K * 3;  // second output section

    const size_t need = (size_t)BATCH * WSF * sizeof(float);  // ~4.3 MB

    fps_kernel<<<BATCH, FPS_T, 0, stream>>>(in, centers);
    if (d_ws != nullptr && ws_size >= need) {
        build_kernel<<<BATCH, BT, 0, stream>>>(in, (float*)d_ws);
        knn_kernel<<<(BATCH * NGRP) / KNN_WPB, KNN_T, 0, stream>>>(
            in, centers, (const float*)d_ws, out);
    } else {
        knn_fallback<<<(BATCH * NGRP) / KNN_WPB_FB, KNN_WPB_FB * 64, 0, stream>>>(
            in, centers, out);
    }
}

// Round 4
// 555.002 us; speedup vs baseline: 1.0494x; 1.0049x over previous
//
#include <hip/hip_runtime.h>

typedef unsigned long long u64;
typedef unsigned int u32;
typedef float v2f __attribute__((ext_vector_type(2)));

// Problem constants (from reference setup_inputs / NUM_GROUP / GROUP_SIZE)
#define BATCH 32
#define NPTS  8192
#define NGRP  512
#define KNN_K 32

#define FPS_T 256                  // fps block (4 waves) -- R4/R11 champion config
#define FPS_W (FPS_T / 64)         // 4 waves
#define PPAIR (NPTS / FPS_T / 2)   // 16 point-PAIRS per thread

#define KNN_WPB 8                  // knn waves per block
#define KNN_T   (KNN_WPB * 64)     // 512 threads
#define QCAP    128                // per-wave LDS candidate buffer depth

#define NCH     (NPTS / 64)        // 128 sorted 64-point chunks per batch
#define GC      16                 // grid cells per axis (16^3 = 4096)
#define NCELL   (GC * GC * GC)
#define QB      512                // quantile-CDF bins per axis
#define BT      512                // build_kernel threads
#define BPT     (NPTS / BT)        // 16 points per build thread
// Workspace layout per batch (floats): sx[8192] sy[8192] sz[8192] sidx[8192(u32)] aabb[128*6]
#define WSF     (4 * NPTS + NCH * 6)   // 33536 floats per batch

// Exact IEEE (no FMA contraction) squared distance: ((dx*dx + dy*dy) + dz*dz)
__device__ __forceinline__ float sq3(float dx, float dy, float dz) {
    return __fadd_rn(__fadd_rn(__fmul_rn(dx, dx), __fmul_rn(dy, dy)), __fmul_rn(dz, dz));
}

// d >= 0 always -> IEEE bits order-monotonic; u64 ascending == (d, idx) lex.
__device__ __forceinline__ u64 packdi(float d, int n) {
    return ((u64)__float_as_uint(d) << 32) | (u32)n;
}

__device__ __forceinline__ u64 umin64(u64 a, u64 b) { return a < b ? a : b; }
__device__ __forceinline__ u64 umax64(u64 a, u64 b) { return a > b ? a : b; }

__device__ __forceinline__ u64 shfl_xor_u64(u64 v, int m) {
    int lo = __shfl_xor((int)(u32)v, m, 64);
    int hi = __shfl_xor((int)(u32)(v >> 32), m, 64);
    return ((u64)(u32)hi << 32) | (u32)lo;
}

__device__ __forceinline__ u64 shfl_u64(u64 v, int src) {
    int lo = __shfl((int)(u32)v, src, 64);
    int hi = __shfl((int)(u32)(v >> 32), src, 64);
    return ((u64)(u32)hi << 32) | (u32)lo;
}

// ---- DPP wave-64 u64-max reduction (result valid in lane 63) --------------
// update_dpp(old=0, bound_ctrl=1): invalid-source lanes read 0; 0 is a safe
// identity (for the min-pick use below, key ~0 means "consumed" and ~key==0).
template <int CTRL>
__device__ __forceinline__ u64 dpp_max_step(u64 k) {
    u32 plo = (u32)__builtin_amdgcn_update_dpp(0, (int)(u32)k, CTRL, 0xF, 0xF, true);
    u32 phi = (u32)__builtin_amdgcn_update_dpp(0, (int)(u32)(k >> 32), CTRL, 0xF, 0xF, true);
    u64 p = ((u64)phi << 32) | plo;
    return k > p ? k : p;
}
__device__ __forceinline__ u64 dpp_wave_max(u64 k) {
    k = dpp_max_step<0x111>(k);  // row_shr:1
    k = dpp_max_step<0x112>(k);  // row_shr:2
    k = dpp_max_step<0x114>(k);  // row_shr:4
    k = dpp_max_step<0x118>(k);  // row_shr:8
    k = dpp_max_step<0x142>(k);  // row_bcast15
    k = dpp_max_step<0x143>(k);  // row_bcast31 -> lane63 = full wave
    return k;
}

// Cross-lane bitonic sort: one u64 per lane -> ascending by lane index.
__device__ __forceinline__ u64 lane_sort64(u64 v, int lane) {
#pragma unroll
    for (int k = 2; k <= 64; k <<= 1) {
#pragma unroll
        for (int j = k >> 1; j > 0; j >>= 1) {
            u64 p = shfl_xor_u64(v, j);
            bool keepmin = (((lane & k) == 0) == ((lane & j) == 0));
            u64 mn = umin64(v, p), mx = umax64(v, p);
            v = keepmin ? mn : mx;
        }
    }
    return v;
}

// m, c ascending-sorted across lanes -> lowest 64 of the 128, sorted.
__device__ __forceinline__ u64 lane_merge64(u64 m, u64 c, int lane) {
    u64 cr = shfl_xor_u64(c, 63);
    u64 z = umin64(m, cr);
#pragma unroll
    for (int dd = 32; dd > 0; dd >>= 1) {
        u64 p = shfl_xor_u64(z, dd);
        u64 mn = umin64(z, p), mx = umax64(z, p);
        z = (lane & dd) ? mx : mn;
    }
    return z;
}

// One knn scan step: tau-filter + ballot-compacted LDS append + batched flush
__device__ __forceinline__ void knn_step(u64& m, u64& tau, int& cnt, u64* sbuf,
                                         float x, float y, float z,
                                         float cx, float cy, float cz,
                                         int n, int lane) {
    float d = sq3(__fsub_rn(x, cx), __fsub_rn(y, cy), __fsub_rn(z, cz));
    u64 kk = packdi(d, n);
    bool cand = kk < tau;  // strict: excluded keys provably > global 32nd
    u64 mask = __ballot(cand);
    if (mask) {
        u32 below = __builtin_amdgcn_mbcnt_hi(
            (u32)(mask >> 32), __builtin_amdgcn_mbcnt_lo((u32)mask, 0));
        if (cand) sbuf[cnt + below] = kk;
        cnt += (int)__popcll(mask);
        if (cnt >= 64) {
            u64 c = sbuf[lane];
            c = lane_sort64(c, lane);
            m = lane_merge64(m, c, lane);
            tau = shfl_u64(m, 31);
            int rem = cnt - 64;
            if (lane < rem) sbuf[lane] = sbuf[64 + lane];
            cnt = rem;
        }
    }
}

// ---------------------------------------------------------------------------
// FPS (R4/R11 champion, 418 us measured across sessions): one block per
// batch, 256 threads, 32 points/thread as 16 float2 pairs (contract(off):
// per-op IEEE rounding == numpy). In-loop strict-> (bd,bi) tracking per
// half; u64 (d_bits,~n) pack, 6-step DPP wave argmax, single barrier,
// double-buffered 4-partial exchange, scalar b32 coord broadcasts,
// LDS-buffered centers. 7 alternative structures all regressed -- do not
// touch. UNCHANGED this round (isolated knn-prune-quality experiment).
// ---------------------------------------------------------------------------
__global__ __launch_bounds__(FPS_T) void fps_kernel(const float* __restrict__ in,
                                                    float* __restrict__ centers) {
#pragma clang fp contract(off)
    __shared__ float sx[NPTS];           // 32 KB
    __shared__ float sy[NPTS];           // 32 KB
    __shared__ float sz[NPTS];           // 32 KB
    __shared__ u64 s_key[2][FPS_W];      // double-buffered wave partials
    __shared__ float s_out[NGRP * 3];    // 6 KB center-coord buffer

    const int b = blockIdx.x;
    const int t = threadIdx.x;
    const int w = t >> 6;
    const float* xp = in + (size_t)b * 3 * NPTS;
    const float* yp = xp + NPTS;
    const float* zp = xp + 2 * NPTS;

    v2f xr[PPAIR], yr[PPAIR], zr[PPAIR], md[PPAIR];
#pragma unroll
    for (int i = 0; i < PPAIR; ++i) {
        int n = i * (2 * FPS_T) + 2 * t;       // pair covers points n, n+1
        xr[i] = *(const v2f*)(xp + n);
        yr[i] = *(const v2f*)(yp + n);
        zr[i] = *(const v2f*)(zp + n);
        *(v2f*)(sx + n) = xr[i];
        *(v2f*)(sy + n) = yr[i];
        *(v2f*)(sz + n) = zr[i];
        md[i] = (v2f){1e10f, 1e10f};
    }
    __syncthreads();

    int cur = 0;
    for (int r = 0; r < NGRP; ++r) {
        const float cx = sx[cur], cy = sy[cur], cz = sz[cur];  // b32 broadcasts
        if (t == 0) {  // idxs[r] is the PRE-update farthest -> buffer coords
            s_out[r * 3 + 0] = cx;
            s_out[r * 3 + 1] = cy;
            s_out[r * 3 + 2] = cz;
        }

        float bd0 = -1.0f, bd1 = -1.0f;
        int   bi0 = 0,     bi1 = 0;
#pragma unroll
        for (int i = 0; i < PPAIR; ++i) {
            v2f dx = xr[i] - cx;
            v2f dy = yr[i] - cy;
            v2f dz = zr[i] - cz;
            v2f dd = dx * dx + dy * dy + dz * dz;  // contract(off): 3 mul + 2 add
            md[i] = __builtin_elementwise_min(md[i], dd);
            int n = i * (2 * FPS_T) + 2 * t;
            if (md[i].x > bd0) { bd0 = md[i].x; bi0 = n; }      // strict >: first max
            if (md[i].y > bd1) { bd1 = md[i].y; bi1 = n + 1; }
        }
        // max (d, tie -> lowest n) == u64 max of (d_bits, ~n)
        u64 k0 = ((u64)__float_as_uint(bd0) << 32) | (u32)(~(u32)bi0);
        u64 k1 = ((u64)__float_as_uint(bd1) << 32) | (u32)(~(u32)bi1);
        u64 k = dpp_wave_max(umax64(k0, k1));
        if ((t & 63) == 63) s_key[r & 1][w] = k;  // lane 63 holds wave winner
        __syncthreads();
        u64 m = umax64(umax64(s_key[r & 1][0], s_key[r & 1][1]),
                       umax64(s_key[r & 1][2], s_key[r & 1][3]));
        cur = (int)(~(u32)m);  // recover winning index
    }

    __syncthreads();  // t0's last s_out writes
    float* cdst = centers + (size_t)b * NGRP * 3;
    for (int i = t; i < NGRP * 3; i += FPS_T) cdst[i] = s_out[i];
}

// ---------------------------------------------------------------------------
// build_kernel v2: QUANTILE-WARPED Morton counting-sort + per-chunk AABBs.
// R3 post-mortem: raw-coordinate Morton gave ~60-pt core cells (tight) but
// near-empty peripheral cells -> 64-point runs in the tails spanned huge
// Z-ranges -> lb~0 AABBs exactly where FPS centers live (periphery) -> weak
// pruning (V~80 of 128). Fix: per-axis empirical-CDF warp (512-bin histogram
// + scan -> 16 balanced 512-point slices per axis) before Morton binning.
// Now every cell holds ~2 points uniformly and every 64-point chunk is a
// compact quantile-space box, periphery included. Ordering-only change:
// AABBs still computed from actual points in original space, knn selection
// is scan-order-independent lex-min -> output bits unaffected.
// ---------------------------------------------------------------------------
__device__ __forceinline__ int qbin(float v) {  // 512 bins over [-4,4]
    int c = (int)((v + 4.0f) * 64.0f);
    c = c < 0 ? 0 : c;
    return c > (QB - 1) ? (QB - 1) : c;
}
__device__ __forceinline__ u32 part3_4(u32 v) {  // spread 4 bits to bits 0,3,6,9
    return (v & 1u) | ((v & 2u) << 2) | ((v & 4u) << 4) | ((v & 8u) << 6);
}

__global__ __launch_bounds__(BT) void build_kernel(const float* __restrict__ in,
                                                   float* __restrict__ ws) {
    __shared__ u32 hist[NCELL];     // 16 KB
    __shared__ u32 hq[3][QB];       // 6 KB axis histograms -> cell LUTs
    __shared__ float sxl[NPTS];     // 32 KB
    __shared__ float syl[NPTS];     // 32 KB
    __shared__ float szl[NPTS];     // 32 KB  (total ~118 KB; 1 block/CU, fine)
    __shared__ u32 wtot[3][BT / 64];

    const int b = blockIdx.x;
    const int t = threadIdx.x;
    const int lane = t & 63;
    const int w = t >> 6;
    const float* xp = in + (size_t)b * 3 * NPTS;
    const float* yp = xp + NPTS;
    const float* zp = xp + 2 * NPTS;
    float* wsb = ws + (size_t)b * WSF;
    float* ws_sx = wsb;
    float* ws_sy = wsb + NPTS;
    float* ws_sz = wsb + 2 * NPTS;
    u32*   ws_si = (u32*)(wsb + 3 * NPTS);
    float* ws_ab = wsb + 4 * NPTS;

    for (int i = t; i < NCELL; i += BT) hist[i] = 0;
    for (int i = t; i < 3 * QB; i += BT) (&hq[0][0])[i] = 0;
    __syncthreads();

    // load points (kept in regs for the whole kernel) + per-axis histograms
    float px[BPT], py[BPT], pz[BPT];
#pragma unroll
    for (int i = 0; i < BPT; ++i) {
        int n = i * BT + t;  // coalesced
        px[i] = xp[n]; py[i] = yp[n]; pz[i] = zp[n];
        atomicAdd(&hq[0][qbin(px[i])], 1u);
        atomicAdd(&hq[1][qbin(py[i])], 1u);
        atomicAdd(&hq[2][qbin(pz[i])], 1u);
    }
    __syncthreads();

    // exclusive-scan each 512-bin histogram (1 bin/thread), then convert in
    // place to a quantile-cell LUT: cell = excl_cdf >> 9  (16 x 512-pt slices)
    {
        u32 v0 = hq[0][t], v1 = hq[1][t], v2 = hq[2][t];
        u32 x0 = v0, x1 = v1, x2 = v2;
#pragma unroll
        for (int d = 1; d < 64; d <<= 1) {
            u32 y0 = __shfl_up(x0, d, 64), y1 = __shfl_up(x1, d, 64), y2 = __shfl_up(x2, d, 64);
            if (lane >= d) { x0 += y0; x1 += y1; x2 += y2; }
        }
        if (lane == 63) { wtot[0][w] = x0; wtot[1][w] = x1; wtot[2][w] = x2; }
        __syncthreads();
        u32 b0 = 0, b1 = 0, b2 = 0;
        for (int j = 0; j < w; ++j) { b0 += wtot[0][j]; b1 += wtot[1][j]; b2 += wtot[2][j]; }
        hq[0][t] = (b0 + x0 - v0) >> 9;   // <= 8191>>9 = 15, always 4-bit
        hq[1][t] = (b1 + x1 - v1) >> 9;
        hq[2][t] = (b2 + x2 - v2) >> 9;
    }
    __syncthreads();

    // Morton code on warped cells + counting histogram
    int pc[BPT];
#pragma unroll
    for (int i = 0; i < BPT; ++i) {
        u32 cxq = hq[0][qbin(px[i])];
        u32 cyq = hq[1][qbin(py[i])];
        u32 czq = hq[2][qbin(pz[i])];
        pc[i] = (int)(part3_4(cxq) | (part3_4(cyq) << 1) | (part3_4(czq) << 2));
        atomicAdd(&hist[pc[i]], 1u);
    }
    __syncthreads();

    // exclusive scan of hist[4096]: 8 cells/thread + wave scan + cross-wave
    u32 h[NCELL / BT];
    u32 lsum = 0;
#pragma unroll
    for (int j = 0; j < NCELL / BT; ++j) { h[j] = hist[t * (NCELL / BT) + j]; lsum += h[j]; }
    u32 x = lsum;
#pragma unroll
    for (int d = 1; d < 64; d <<= 1) {
        u32 y = __shfl_up(x, d, 64);
        if (lane >= d) x += y;
    }
    if (lane == 63) wtot[0][w] = x;
    u32 wexcl = x - lsum;
    __syncthreads();
    u32 base = 0;
    for (int j = 0; j < w; ++j) base += wtot[0][j];
    u32 run = base + wexcl;
#pragma unroll
    for (int j = 0; j < NCELL / BT; ++j) {
        u32 c = h[j];
        hist[t * (NCELL / BT) + j] = run;
        run += c;
    }
    __syncthreads();

    // scatter into LDS (coords) + global (orig index)
#pragma unroll
    for (int i = 0; i < BPT; ++i) {
        u32 pos = atomicAdd(&hist[pc[i]], 1u);
        sxl[pos] = px[i]; syl[pos] = py[i]; szl[pos] = pz[i];
        ws_si[pos] = (u32)(i * BT + t);
    }
    __syncthreads();

    // write sorted coords out, coalesced
    for (int i = t; i < NPTS; i += BT) {
        ws_sx[i] = sxl[i]; ws_sy[i] = syl[i]; ws_sz[i] = szl[i];
    }
    // per-chunk AABB: 128 chunks / 8 waves
    for (int q = w; q < NCH; q += BT / 64) {
        int p = q * 64 + lane;
        float X = sxl[p], Y = syl[p], Z = szl[p];
        float xlo = X, xhi = X, ylo = Y, yhi = Y, zlo = Z, zhi = Z;
#pragma unroll
        for (int d = 1; d < 64; d <<= 1) {
            xlo = fminf(xlo, __shfl_xor(xlo, d, 64)); xhi = fmaxf(xhi, __shfl_xor(xhi, d, 64));
            ylo = fminf(ylo, __shfl_xor(ylo, d, 64)); yhi = fmaxf(yhi, __shfl_xor(yhi, d, 64));
            zlo = fminf(zlo, __shfl_xor(zlo, d, 64)); zhi = fmaxf(zhi, __shfl_xor(zhi, d, 64));
        }
        if (lane == 0) {
            float* a = ws_ab + q * 6;
            a[0] = xlo; a[1] = xhi; a[2] = ylo; a[3] = yhi; a[4] = zlo; a[5] = zhi;
        }
    }
}

// ---------------------------------------------------------------------------
// kNN v3 (UNCHANGED from R3): chunk-pruned exact top-32. Per wave: 128 chunk
// AABB lower bounds (2/lane, in regs as (lb_bits<<32)|chunk u64 keys),
// DPP-min-pick nearest chunk, seed exact top-64 from it, then
// pick+tau-filter until lb*0.999 > tau_d (margin >> float rounding error ->
// skips provably can't touch the exact top-32; processed points use the
// identical sq3/key arithmetic as the full scan).
// ---------------------------------------------------------------------------
__global__ __launch_bounds__(KNN_T) void knn_kernel(const float* __restrict__ in,
                                                    const float* __restrict__ centers,
                                                    const float* __restrict__ ws,
                                                    float* __restrict__ out) {
    __shared__ float s_ab[NCH * 6];      // 3 KB chunk AABBs (shared: whole block same batch)
    __shared__ u64 sbuf[KNN_WPB][QCAP];  // 8 KB candidate buffers

    const int wave = threadIdx.x >> 6;
    const int lane = threadIdx.x & 63;
    const int cid  = blockIdx.x * KNN_WPB + wave;   // [0, B*G); 8 waves same batch
    const int b    = cid >> 9;                      // /NGRP

    const float* xp = in + (size_t)b * 3 * NPTS;
    const float* yp = xp + NPTS;
    const float* zp = xp + 2 * NPTS;
    const float* wsb = ws + (size_t)b * WSF;
    const float* sxs = wsb;
    const float* sys = wsb + NPTS;
    const float* szs = wsb + 2 * NPTS;
    const u32*   sidx = (const u32*)(wsb + 3 * NPTS);
    const float* ab = wsb + 4 * NPTS;

    for (int i = threadIdx.x; i < NCH * 6; i += KNN_T) s_ab[i] = ab[i];
    __syncthreads();

    const float cx = centers[cid * 3 + 0];
    const float cy = centers[cid * 3 + 1];
    const float cz = centers[cid * 3 + 2];

    // per-lane lower-bound keys for chunks lane and lane+64
    u64 k0, k1;
    {
        const float* a0 = &s_ab[lane * 6];
        float dx = fmaxf(fmaxf(__fsub_rn(a0[0], cx), __fsub_rn(cx, a0[1])), 0.0f);
        float dy = fmaxf(fmaxf(__fsub_rn(a0[2], cy), __fsub_rn(cy, a0[3])), 0.0f);
        float dz = fmaxf(fmaxf(__fsub_rn(a0[4], cz), __fsub_rn(cz, a0[5])), 0.0f);
        k0 = ((u64)__float_as_uint(dx * dx + dy * dy + dz * dz) << 32) | (u32)lane;
        const float* a1 = &s_ab[(lane + 64) * 6];
        dx = fmaxf(fmaxf(__fsub_rn(a1[0], cx), __fsub_rn(cx, a1[1])), 0.0f);
        dy = fmaxf(fmaxf(__fsub_rn(a1[2], cy), __fsub_rn(cy, a1[3])), 0.0f);
        dz = fmaxf(fmaxf(__fsub_rn(a1[4], cz), __fsub_rn(cz, a1[5])), 0.0f);
        k1 = ((u64)__float_as_uint(dx * dx + dy * dy + dz * dz) << 32) | (u32)(lane + 64);
    }

    u64 m, tau;
    int cnt = 0;

    // seed: nearest chunk, exact sorted top-64
    {
        u64 inv = dpp_wave_max(~umin64(k0, k1));
        u64 got = ~shfl_u64(inv, 63);
        int c = (int)(u32)got;
        int p = c * 64 + lane;
        float X = sxs[p], Y = sys[p], Z = szs[p];
        int n = (int)sidx[p];
        m = lane_sort64(packdi(sq3(__fsub_rn(X, cx), __fsub_rn(Y, cy), __fsub_rn(Z, cz)), n),
                        lane);
        tau = shfl_u64(m, 31);
        if (lane == (c & 63)) { if (c < 64) k0 = ~0ull; else k1 = ~0ull; }
    }

    // pick+filter loop: chunks in ascending lb order, sound early break
    for (int it = 1; it < NCH; ++it) {
        u64 inv = dpp_wave_max(~umin64(k0, k1));
        u64 got = ~shfl_u64(inv, 63);
        float lb = __uint_as_float((u32)(got >> 32));
        float tau_d = __uint_as_float((u32)(tau >> 32));
        if (lb * 0.999f > tau_d) break;  // all remaining chunks provably > 32nd
        int c = (int)(u32)got;
        int p = c * 64 + lane;
        float X = sxs[p], Y = sys[p], Z = szs[p];
        int n = (int)sidx[p];
        knn_step(m, tau, cnt, sbuf[wave], X, Y, Z, cx, cy, cz, n, lane);
        if (lane == (c & 63)) { if (c < 64) k0 = ~0ull; else k1 = ~0ull; }
    }

    // drain leftovers (<= 127 keys -> at most 2 batches)
    while (cnt > 0) {
        int take = cnt < 64 ? cnt : 64;
        u64 v = sbuf[wave][lane];
        u64 c = (lane < take) ? v : ~0ull;
        c = lane_sort64(c, lane);
        m = lane_merge64(m, c, lane);
        int rem = cnt - take;
        if (lane < rem) sbuf[wave][lane] = sbuf[wave][64 + lane];
        cnt = rem;
    }

    // lanes 0..31 hold the exact global top-32, ascending (== stable top_k)
    if (lane < KNN_K) {
        int n = (int)(u32)m;
        size_t o = (size_t)cid * (KNN_K * 3) + (size_t)lane * 3;
        out[o + 0] = __fsub_rn(xp[n], cx);
        out[o + 1] = __fsub_rn(yp[n], cy);
        out[o + 2] = __fsub_rn(zp[n], cz);
    }
}

// ---------------------------------------------------------------------------
// Fallback knn (R0 champion, full scan) -- used only if ws_size is too small.
// ---------------------------------------------------------------------------
#define KNN_WPB_FB 4
__global__ __launch_bounds__(KNN_WPB_FB * 64) void knn_fallback(
    const float* __restrict__ in, const float* __restrict__ centers,
    float* __restrict__ out) {
    __shared__ u64 sbuf[KNN_WPB_FB][QCAP];

    const int wave = threadIdx.x >> 6;
    const int lane = threadIdx.x & 63;
    const int cid  = blockIdx.x * KNN_WPB_FB + wave;
    const int b    = cid >> 9;

    const float* xp = in + (size_t)b * 3 * NPTS;
    const float* yp = xp + NPTS;
    const float* zp = xp + 2 * NPTS;

    const float cx = centers[cid * 3 + 0];
    const float cy = centers[cid * 3 + 1];
    const float cz = centers[cid * 3 + 2];

    float x = xp[lane], y = yp[lane], z = zp[lane];
    u64 m = packdi(sq3(__fsub_rn(x, cx), __fsub_rn(y, cy), __fsub_rn(z, cz)), lane);
    m = lane_sort64(m, lane);
    u64 tau = shfl_u64(m, 31);
    int cnt = 0;

    int j = 1;
#pragma unroll 1
    for (; j + 3 < NPTS / 64; j += 4) {
        int n0 = j * 64 + lane, n1 = n0 + 64, n2 = n0 + 128, n3 = n0 + 192;
        float x0 = xp[n0], y0 = yp[n0], z0 = zp[n0];
        float x1 = xp[n1], y1 = yp[n1], z1 = zp[n1];
        float x2 = xp[n2], y2 = yp[n2], z2 = zp[n2];
        float x3 = xp[n3], y3 = yp[n3], z3 = zp[n3];
        knn_step(m, tau, cnt, sbuf[wave], x0, y0, z0, cx, cy, cz, n0, lane);
        knn_step(m, tau, cnt, sbuf[wave], x1, y1, z1, cx, cy, cz, n1, lane);
        knn_step(m, tau, cnt, sbuf[wave], x2, y2, z2, cx, cy, cz, n2, lane);
        knn_step(m, tau, cnt, sbuf[wave], x3, y3, z3, cx, cy, cz, n3, lane);
    }
    for (; j < NPTS / 64; ++j) {
        int n = j * 64 + lane;
        knn_step(m, tau, cnt, sbuf[wave], xp[n], yp[n], zp[n], cx, cy, cz, n, lane);
    }
    while (cnt > 0) {
        int take = cnt < 64 ? cnt : 64;
        u64 v = sbuf[wave][lane];
        u64 c = (lane < take) ? v : ~0ull;
        c = lane_sort64(c, lane);
        m = lane_merge64(m, c, lane);
        int rem = cnt - take;
        if (lane < rem) sbuf[wave][lane] = sbuf[wave][64 + lane];
        cnt = rem;
    }
    if (lane < KNN_K) {
        int n = (int)(u32)m;
        size_t o = (size_t)cid * (KNN_K * 3) + (size_t)lane * 3;
        out[o + 0] = __fsub_rn(xp[n], cx);
        out[o + 1] = __fsub_rn(yp[n], cy);
        out[o + 2] = __fsub_rn(zp[n], cz);
    }
}

extern "C" void kernel_launch(void* const* d_in, const int* in_sizes, int n_in,
                              void* d_out, int out_size, void* d_ws, size_t ws_size,
                              hipStream_t stream) {
    const float* in  = (const float*)d_in[0];
    float* out       = (float*)d_out;
    float* centers   = out + (size_t)BATCH * NGRP * KNN_K * 3;  // second output section

    const size_t need = (size_t)BATCH * WSF * sizeof(float);  // ~4.3 MB

    fps_kernel<<<BATCH, FPS_T, 0, stream>>>(in, centers);
    if (d_ws != nullptr && ws_size >= need) {
        build_kernel<<<BATCH, BT, 0, stream>>>(in, (float*)d_ws);
        knn_kernel<<<(BATCH * NGRP) / KNN_WPB, KNN_T, 0, stream>>>(
            in, centers, (const float*)d_ws, out);
    } else {
        knn_fallback<<<(BATCH * NGRP) / KNN_WPB_FB, KNN_WPB_FB * 64, 0, stream>>>(
            in, centers, out);
    }
}